// Round 7
// baseline (612.315 us; speedup 1.0000x reference)
//
#include <hip/hip_runtime.h>
#include <hip/hip_bf16.h>

#define HH 1024
#define BB 32
#define TT 2048

typedef __attribute__((ext_vector_type(8))) short bf16x8;
typedef __attribute__((ext_vector_type(4))) float f32x4;

static __device__ __forceinline__ unsigned short f2bf(float f) {
    unsigned int u = __float_as_uint(f);
    unsigned int r = u + 0x7fffu + ((u >> 16) & 1u);
    return (unsigned short)(r >> 16);
}
static __device__ __forceinline__ float bf2f(unsigned short u) {
    return __uint_as_float(((unsigned int)u) << 16);
}
// tanh(x) = 1 - 2/(1+e^{2x}); exact at limits, err ~1e-6
static __device__ __forceinline__ float fast_tanh(float x) {
    float e = __expf(2.0f * x);
    return 1.0f - 2.0f / (e + 1.0f);
}

// ---- convert Wa_w (fp32 [H][H]) to bf16 in ws ----
__global__ void k_convW(const float* __restrict__ W, unsigned short* __restrict__ Wb) {
    int i = blockIdx.x * 256 + threadIdx.x;
    float4 v = ((const float4*)W)[i];
    ushort4 o;
    o.x = f2bf(v.x); o.y = f2bf(v.y); o.z = f2bf(v.z); o.w = f2bf(v.w);
    ((ushort4*)Wb)[i] = o;
}

// ---- convert enc (fp32 [B*T*H]) to bf16 in ws: 8 elems/thread ----
__global__ void k_convEnc(const float* __restrict__ E, unsigned short* __restrict__ Eb) {
    long i = ((long)blockIdx.x * 256 + threadIdx.x) * 8;
    float4 a = *(const float4*)(E + i);
    float4 b = *(const float4*)(E + i + 4);
    ushort4 o0, o1;
    o0.x = f2bf(a.x); o0.y = f2bf(a.y); o0.z = f2bf(a.z); o0.w = f2bf(a.w);
    o1.x = f2bf(b.x); o1.y = f2bf(b.y); o1.z = f2bf(b.z); o1.w = f2bf(b.w);
    *(ushort4*)(Eb + i) = o0;
    *(ushort4*)(Eb + i + 4) = o1;
}

// ---- dec_proj[b][o] = dot(dec[b,:], Ua_w[o,:]) + Ua_b[o] + Wa_b[o] ----
__global__ void k_decproj(const float* __restrict__ dec, const float* __restrict__ Ua,
                          const float* __restrict__ Uab, const float* __restrict__ Wab,
                          float* __restrict__ dp) {
    int gtid = blockIdx.x * 256 + threadIdx.x;   // 32768
    int b = gtid >> 10, o = gtid & 1023;
    const float4* d4 = (const float4*)(dec + (long)b * HH);
    const float4* u4 = (const float4*)(Ua + (long)o * HH);
    float acc = 0.f;
    for (int k = 0; k < HH / 4; ++k) {
        float4 a = d4[k], w = u4[k];
        acc += a.x * w.x + a.y * w.y + a.z * w.z + a.w * w.w;
    }
    dp[gtid] = acc + Uab[o] + Wab[o];
}

// ============ FAST PATH: barrier-free direct-from-L2 bf16 GEMM ============
// No LDS, no barriers. Each MFMA fragment is a contiguous 16B lane chunk,
// loaded straight from global (B=Wa_w is L2-resident 2MB; A=enc bf16 gets
// XCD-grouped L2 reuse). 128x128 block = 2x2 waves of 64x64 each.
__global__ __launch_bounds__(256, 2) void k_score_bf(
        const unsigned short* __restrict__ encb, const unsigned short* __restrict__ Wb,
        const float* __restrict__ dp, const float* __restrict__ vw,
        float* __restrict__ scores) {
    int bid = blockIdx.x;
    // XCD-aware: each XCD walks nt=0..7 (same A-tile -> its L2), then next mt.
    int xcd = bid & 7;
    int ord = bid >> 3;
    int nt = ord & 7;
    int mt = (ord >> 3) * 8 + xcd;
    long m0 = (long)mt * 128;
    int o0 = nt * 128;
    int tid = threadIdx.x;
    int lane = tid & 63, wid = tid >> 6;
    int wm = wid >> 1, wn = wid & 1;
    int r = lane & 15, g = lane >> 4;

    f32x4 acc[4][4];
    #pragma unroll
    for (int i = 0; i < 4; ++i)
        #pragma unroll
        for (int j = 0; j < 4; ++j) acc[i][j] = (f32x4){0.f, 0.f, 0.f, 0.f};

    // lane's fragment base: row (.. + r), k-chunk g*8 within each 32-slice
    const unsigned short* aB = encb + (m0 + wm * 64 + r) * (long)HH + g * 8;
    const unsigned short* bB = Wb + ((long)(o0 + wn * 64 + r)) * HH + g * 8;

    #pragma unroll 2
    for (int kc = 0; kc < HH; kc += 64) {
        bf16x8 af[4][2], bf[4][2];
        #pragma unroll
        for (int mi = 0; mi < 4; ++mi)
            #pragma unroll
            for (int ks = 0; ks < 2; ++ks)
                af[mi][ks] = *(const bf16x8*)(aB + (long)mi * 16 * HH + kc + ks * 32);
        #pragma unroll
        for (int ni = 0; ni < 4; ++ni)
            #pragma unroll
            for (int ks = 0; ks < 2; ++ks)
                bf[ni][ks] = *(const bf16x8*)(bB + (long)ni * 16 * HH + kc + ks * 32);
        #pragma unroll
        for (int mi = 0; mi < 4; ++mi)
            #pragma unroll
            for (int ni = 0; ni < 4; ++ni)
                #pragma unroll
                for (int ks = 0; ks < 2; ++ks)
                    acc[mi][ni] = __builtin_amdgcn_mfma_f32_16x16x32_bf16(
                        af[mi][ks], bf[ni][ks], acc[mi][ni], 0, 0, 0);
    }

    // epilogue: scores[m] += sum_o tanh(acc + dp[b][o]) * v[o]
    int bb = (int)(m0 >> 11);
    float vv[4], dpv[4];
    #pragma unroll
    for (int ni = 0; ni < 4; ++ni) {
        int o = o0 + wn * 64 + ni * 16 + r;
        vv[ni] = vw[o];
        dpv[ni] = dp[bb * HH + o];
    }
    #pragma unroll
    for (int mi = 0; mi < 4; ++mi) {
        float vp[4] = {0.f, 0.f, 0.f, 0.f};
        #pragma unroll
        for (int ni = 0; ni < 4; ++ni)
            #pragma unroll
            for (int j = 0; j < 4; ++j)
                vp[j] += fast_tanh(acc[mi][ni][j] + dpv[ni]) * vv[ni];
        #pragma unroll
        for (int j = 0; j < 4; ++j) {
            float s = vp[j];
            s += __shfl_xor(s, 1); s += __shfl_xor(s, 2);
            s += __shfl_xor(s, 4); s += __shfl_xor(s, 8);
            if (r == 0) {
                int row = wm * 64 + mi * 16 + g * 4 + j;
                atomicAdd(&scores[m0 + row], s);
            }
        }
    }
}

// ================= FALLBACK: fp32-staged GEMM =================
#define LDSP 40
__global__ __launch_bounds__(256) void k_score(const float* __restrict__ enc,
        const unsigned short* __restrict__ Wb, const float* __restrict__ dp,
        const float* __restrict__ vw, float* __restrict__ scores) {
    __shared__ __align__(16) unsigned short As[128][LDSP];
    __shared__ __align__(16) unsigned short Bs[128][LDSP];
    int bid = blockIdx.x;
    int nt = bid & 7;
    int mt = bid >> 3;
    long m0 = (long)mt * 128;
    int o0 = nt * 128;
    int tid = threadIdx.x;
    int lane = tid & 63, wid = tid >> 6;
    int wm = wid >> 1, wn = wid & 1;
    int r = lane & 15, g = lane >> 4;

    f32x4 acc[4][4];
    #pragma unroll
    for (int i = 0; i < 4; ++i)
        #pragma unroll
        for (int j = 0; j < 4; ++j) acc[i][j] = (f32x4){0.f, 0.f, 0.f, 0.f};

    for (int kc = 0; kc < HH; kc += 32) {
        #pragma unroll
        for (int i = 0; i < 4; ++i) {
            int idx = tid + i * 256;
            int row = idx >> 3, kq = idx & 7;
            float4 a = *(const float4*)(enc + (m0 + row) * HH + kc + kq * 4);
            ushort4 p;
            p.x = f2bf(a.x); p.y = f2bf(a.y); p.z = f2bf(a.z); p.w = f2bf(a.w);
            *(ushort4*)(&As[row][kq * 4]) = p;
        }
        #pragma unroll
        for (int i = 0; i < 2; ++i) {
            int idx = tid + i * 256;
            int row = idx >> 2, kq = idx & 3;
            *(int4*)(&Bs[row][kq * 8]) =
                *(const int4*)(Wb + (long)(o0 + row) * HH + kc + kq * 8);
        }
        __syncthreads();
        bf16x8 af[4], bfr[4];
        #pragma unroll
        for (int mi = 0; mi < 4; ++mi)
            af[mi] = *(const bf16x8*)(&As[wm * 64 + mi * 16 + r][g * 8]);
        #pragma unroll
        for (int ni = 0; ni < 4; ++ni)
            bfr[ni] = *(const bf16x8*)(&Bs[wn * 64 + ni * 16 + r][g * 8]);
        #pragma unroll
        for (int mi = 0; mi < 4; ++mi)
            #pragma unroll
            for (int ni = 0; ni < 4; ++ni)
                acc[mi][ni] = __builtin_amdgcn_mfma_f32_16x16x32_bf16(
                    af[mi], bfr[ni], acc[mi][ni], 0, 0, 0);
        __syncthreads();
    }

    int bb = (int)(m0 >> 11);
    #pragma unroll
    for (int mi = 0; mi < 4; ++mi) {
        float vp[4] = {0.f, 0.f, 0.f, 0.f};
        #pragma unroll
        for (int ni = 0; ni < 4; ++ni) {
            int o = o0 + wn * 64 + ni * 16 + r;
            float vvs = vw[o];
            float dpvs = dp[bb * HH + o];
            #pragma unroll
            for (int j = 0; j < 4; ++j)
                vp[j] += fast_tanh(acc[mi][ni][j] + dpvs) * vvs;
        }
        #pragma unroll
        for (int j = 0; j < 4; ++j) {
            float s = vp[j];
            s += __shfl_xor(s, 1); s += __shfl_xor(s, 2);
            s += __shfl_xor(s, 4); s += __shfl_xor(s, 8);
            if (r == 0) {
                int row = wm * 64 + mi * 16 + g * 4 + j;
                atomicAdd(&scores[m0 + row], s);
            }
        }
    }
}

// ---- softmax over T per batch row, in-place ----
__global__ void k_softmax(float* __restrict__ w) {
    int b = blockIdx.x;
    float* row = w + (long)b * TT;
    int tid = threadIdx.x;
    float loc[8];
    float m = -1e30f;
    #pragma unroll
    for (int i = 0; i < 8; ++i) { loc[i] = row[tid + i * 256]; m = fmaxf(m, loc[i]); }
    #pragma unroll
    for (int off = 1; off < 64; off <<= 1) m = fmaxf(m, __shfl_xor(m, off));
    __shared__ float red[4];
    if ((tid & 63) == 0) red[tid >> 6] = m;
    __syncthreads();
    m = fmaxf(fmaxf(red[0], red[1]), fmaxf(red[2], red[3]));
    float s = 0.f;
    #pragma unroll
    for (int i = 0; i < 8; ++i) { loc[i] = __expf(loc[i] - m); s += loc[i]; }
    #pragma unroll
    for (int off = 1; off < 64; off <<= 1) s += __shfl_xor(s, off);
    __shared__ float red2[4];
    if ((tid & 63) == 0) red2[tid >> 6] = s;
    __syncthreads();
    s = red2[0] + red2[1] + red2[2] + red2[3];
    float inv = 1.0f / s;
    #pragma unroll
    for (int i = 0; i < 8; ++i) row[tid + i * 256] = loc[i] * inv;
}

// ---- context from bf16 enc: 4 h per thread, ushort4 loads ----
__global__ void k_context_bf(const unsigned short* __restrict__ encb,
                             const float* __restrict__ w, float* __restrict__ ctx) {
    int bid = blockIdx.x;             // 512 = 32 b x 16 ts
    int b = bid >> 4;
    int ts = bid & 15;
    int h = threadIdx.x * 4;
    const float* wr = w + (long)b * TT + ts * 128;
    long base = ((long)b * TT + (long)ts * 128) * HH + h;
    float a0 = 0.f, a1 = 0.f, a2 = 0.f, a3 = 0.f;
    #pragma unroll 4
    for (int t = 0; t < 128; ++t) {
        ushort4 e = *(const ushort4*)(encb + base + (long)t * HH);
        float ww = wr[t];
        a0 += ww * bf2f(e.x);
        a1 += ww * bf2f(e.y);
        a2 += ww * bf2f(e.z);
        a3 += ww * bf2f(e.w);
    }
    atomicAdd(&ctx[b * HH + h], a0);
    atomicAdd(&ctx[b * HH + h + 1], a1);
    atomicAdd(&ctx[b * HH + h + 2], a2);
    atomicAdd(&ctx[b * HH + h + 3], a3);
}

// ---- fallback context (fp32 enc) ----
__global__ void k_context(const float* __restrict__ enc, const float* __restrict__ w,
                          float* __restrict__ ctx) {
    int bid = blockIdx.x;             // 2048
    int b = bid >> 6;
    int hc = (bid >> 4) & 3;
    int ts = bid & 15;
    int h = hc * 256 + threadIdx.x;
    const float* wr = w + (long)b * TT + ts * 128;
    long base = ((long)b * TT + (long)ts * 128) * HH + h;
    float acc = 0.f;
    for (int t = 0; t < 128; ++t)
        acc += wr[t] * enc[base + (long)t * HH];
    atomicAdd(&ctx[b * HH + h], acc);
}

extern "C" void kernel_launch(void* const* d_in, const int* in_sizes, int n_in,
                              void* d_out, int out_size, void* d_ws, size_t ws_size,
                              hipStream_t stream) {
    const float* dec  = (const float*)d_in[0];
    const float* enc  = (const float*)d_in[1];
    const float* Wa_w = (const float*)d_in[2];
    const float* Wa_b = (const float*)d_in[3];
    const float* Ua_w = (const float*)d_in[4];
    const float* Ua_b = (const float*)d_in[5];
    const float* v_w  = (const float*)d_in[6];

    float* out  = (float*)d_out;
    float* ctx  = out;                 // [B][H]
    float* attn = out + BB * HH;       // [B][T]

    float* dpw = (float*)d_ws;                                        // 128 KB
    unsigned short* Wb = (unsigned short*)((char*)d_ws + 131072);     // 2 MB
    unsigned short* encb = (unsigned short*)((char*)d_ws + 131072 + 2097152); // 128 MB
    const size_t NEED = 131072ull + 2097152ull + (size_t)BB * TT * HH * 2;

    hipMemsetAsync(d_out, 0, (size_t)out_size * sizeof(float), stream);
    k_convW<<<1024, 256, 0, stream>>>(Wa_w, Wb);
    k_decproj<<<128, 256, 0, stream>>>(dec, Ua_w, Ua_b, Wa_b, dpw);

    if (ws_size >= NEED) {
        k_convEnc<<<32768, 256, 0, stream>>>(enc, encb);
        k_score_bf<<<4096, 256, 0, stream>>>(encb, Wb, dpw, v_w, attn);
        k_softmax<<<BB, 256, 0, stream>>>(attn);
        k_context_bf<<<512, 256, 0, stream>>>(encb, attn, ctx);
    } else {
        k_score<<<4096, 256, 0, stream>>>(enc, Wb, dpw, v_w, attn);
        k_softmax<<<BB, 256, 0, stream>>>(attn);
        k_context<<<2048, 256, 0, stream>>>(enc, attn, ctx);
    }
}

// Round 8
// 330.189 us; speedup vs baseline: 1.8544x; 1.8544x over previous
//
#include <hip/hip_runtime.h>
#include <hip/hip_bf16.h>

#define HH 1024
#define BB 32
#define TT 2048

typedef __attribute__((ext_vector_type(8))) short bf16x8;
typedef __attribute__((ext_vector_type(4))) float f32x4;

static __device__ __forceinline__ unsigned short f2bf(float f) {
    unsigned int u = __float_as_uint(f);
    unsigned int r = u + 0x7fffu + ((u >> 16) & 1u);
    return (unsigned short)(r >> 16);
}
static __device__ __forceinline__ float bf2f(unsigned short u) {
    return __uint_as_float(((unsigned int)u) << 16);
}
// tanh(x) = 1 - 2/(1+e^{2x}); exact at limits, err ~1e-6
static __device__ __forceinline__ float fast_tanh(float x) {
    float e = __expf(2.0f * x);
    return 1.0f - 2.0f / (e + 1.0f);
}

#define GLOAD_LDS16(gp, lp) \
    __builtin_amdgcn_global_load_lds( \
        (const __attribute__((address_space(1))) void*)(gp), \
        (__attribute__((address_space(3))) void*)(lp), 16, 0, 0)

// ---- convert Wa_w (fp32 [H][H]) to bf16 in ws ----
__global__ void k_convW(const float* __restrict__ W, unsigned short* __restrict__ Wb) {
    int i = blockIdx.x * 256 + threadIdx.x;
    float4 v = ((const float4*)W)[i];
    ushort4 o;
    o.x = f2bf(v.x); o.y = f2bf(v.y); o.z = f2bf(v.z); o.w = f2bf(v.w);
    ((ushort4*)Wb)[i] = o;
}

// ---- convert enc (fp32 [B*T*H]) to bf16 in ws: 8 elems/thread ----
__global__ void k_convEnc(const float* __restrict__ E, unsigned short* __restrict__ Eb) {
    long i = ((long)blockIdx.x * 256 + threadIdx.x) * 8;
    float4 a = *(const float4*)(E + i);
    float4 b = *(const float4*)(E + i + 4);
    ushort4 o0, o1;
    o0.x = f2bf(a.x); o0.y = f2bf(a.y); o0.z = f2bf(a.z); o0.w = f2bf(a.w);
    o1.x = f2bf(b.x); o1.y = f2bf(b.y); o1.z = f2bf(b.z); o1.w = f2bf(b.w);
    *(ushort4*)(Eb + i) = o0;
    *(ushort4*)(Eb + i + 4) = o1;
}

// ---- dec_proj[b][o] = dot(dec[b,:], Ua_w[o,:]) + Ua_b[o] + Wa_b[o] ----
__global__ void k_decproj(const float* __restrict__ dec, const float* __restrict__ Ua,
                          const float* __restrict__ Uab, const float* __restrict__ Wab,
                          float* __restrict__ dp) {
    int gtid = blockIdx.x * 256 + threadIdx.x;   // 32768
    int b = gtid >> 10, o = gtid & 1023;
    const float4* d4 = (const float4*)(dec + (long)b * HH);
    const float4* u4 = (const float4*)(Ua + (long)o * HH);
    float acc = 0.f;
    for (int k = 0; k < HH / 4; ++k) {
        float4 a = d4[k], w = u4[k];
        acc += a.x * w.x + a.y * w.y + a.z * w.z + a.w * w.w;
    }
    dp[gtid] = acc + Uab[o] + Wab[o];
}

// ======= FAST PATH: bf16 GEMM, T2-swizzled LDS, nt-loop amortized =======
// Round-5 proven K-loop (swizzled staging, conflicts=0) wrapped in a loop
// over 4 N-tiles per block. vp accumulates tanh(.)·v across the nt loop in
// registers; scores get ONE 2-way atomicAdd per row at the end (was 8-way).
// Grid 1024: pair-blocks (mt, nh=0/1) consecutive on the same XCD -> the
// shared A-tile is an L2 hit for the second block.
__global__ __launch_bounds__(256) void k_score_bf(
        const unsigned short* __restrict__ encb, const unsigned short* __restrict__ Wb,
        const float* __restrict__ dp, const float* __restrict__ vw,
        float* __restrict__ scores) {
    __shared__ __align__(16) unsigned short As[128 * 64];
    __shared__ __align__(16) unsigned short Bs[128 * 64];
    int bid = blockIdx.x;            // 1024 blocks
    int xcd = bid & 7;
    int ord = bid >> 3;              // 0..127 per XCD
    int nh = ord & 1;                // N-half: nt in [nh*4, nh*4+4)
    int mt = (ord >> 1) * 8 + xcd;   // 0..511, pair (mt,0),(mt,1) same XCD
    long m0 = (long)mt * 128;
    int tid = threadIdx.x;
    int lane = tid & 63, wid = tid >> 6;
    int wm = wid >> 1, wn = wid & 1;
    int r = lane & 15, g = lane >> 4;

    // staging map: lane l, pass p -> LDS row wid*8 + p*32 + l/8, unit l&7.
    // pre-swizzle: load global unit (l&7) ^ (row&7); read XORs unit with row&7.
    int srow = tid >> 3;
    int swu = (tid & 7) ^ (srow & 7);
    const unsigned short* aSrc = encb + (m0 + srow) * HH + swu * 8;
    unsigned short* ldsA = As + wid * 512;   // shorts; +p*2048 per pass
    unsigned short* ldsB = Bs + wid * 512;
    int rx = r & 7;
    int bb = (int)(m0 >> 11);

    float vp[4][4];                  // [mi][j] summed over ALL this block's o
    #pragma unroll
    for (int mi = 0; mi < 4; ++mi)
        #pragma unroll
        for (int j = 0; j < 4; ++j) vp[mi][j] = 0.f;

    #pragma unroll 1
    for (int nt = nh * 4; nt < nh * 4 + 4; ++nt) {
        int o0 = nt * 128;
        const unsigned short* bSrc = Wb + (long)(o0 + srow) * HH + swu * 8;

        f32x4 acc[4][4];
        #pragma unroll
        for (int i = 0; i < 4; ++i)
            #pragma unroll
            for (int j = 0; j < 4; ++j) acc[i][j] = (f32x4){0.f, 0.f, 0.f, 0.f};

        for (int kc = 0; kc < HH; kc += 64) {
            #pragma unroll
            for (int p = 0; p < 4; ++p)
                GLOAD_LDS16(aSrc + kc + p * 32 * HH, ldsA + p * 2048);
            #pragma unroll
            for (int p = 0; p < 4; ++p)
                GLOAD_LDS16(bSrc + kc + p * 32 * HH, ldsB + p * 2048);
            __syncthreads();
            #pragma unroll
            for (int ks = 0; ks < 2; ++ks) {
                int u = ((ks * 4 + g) ^ rx) * 8;   // physical short offset in row
                bf16x8 af[4], bfr[4];
                #pragma unroll
                for (int mi = 0; mi < 4; ++mi)
                    af[mi] = *(const bf16x8*)(&As[(wm * 64 + mi * 16 + r) * 64 + u]);
                #pragma unroll
                for (int ni = 0; ni < 4; ++ni)
                    bfr[ni] = *(const bf16x8*)(&Bs[(wn * 64 + ni * 16 + r) * 64 + u]);
                #pragma unroll
                for (int mi = 0; mi < 4; ++mi)
                    #pragma unroll
                    for (int ni = 0; ni < 4; ++ni)
                        acc[mi][ni] = __builtin_amdgcn_mfma_f32_16x16x32_bf16(
                            af[mi], bfr[ni], acc[mi][ni], 0, 0, 0);
            }
            __syncthreads();
        }

        // fold this nt's contribution into vp (registers only)
        float vv[4], dpv[4];
        #pragma unroll
        for (int ni = 0; ni < 4; ++ni) {
            int o = o0 + wn * 64 + ni * 16 + r;
            vv[ni] = vw[o];
            dpv[ni] = dp[bb * HH + o];
        }
        #pragma unroll
        for (int mi = 0; mi < 4; ++mi)
            #pragma unroll
            for (int ni = 0; ni < 4; ++ni)
                #pragma unroll
                for (int j = 0; j < 4; ++j)
                    vp[mi][j] += fast_tanh(acc[mi][ni][j] + dpv[ni]) * vv[ni];
    }

    // one reduce + one atomic per output row (2 contending blocks: nh=0,1)
    #pragma unroll
    for (int mi = 0; mi < 4; ++mi) {
        #pragma unroll
        for (int j = 0; j < 4; ++j) {
            float s = vp[mi][j];
            s += __shfl_xor(s, 1); s += __shfl_xor(s, 2);
            s += __shfl_xor(s, 4); s += __shfl_xor(s, 8);
            if (r == 0) {
                int row = wm * 64 + mi * 16 + g * 4 + j;
                atomicAdd(&scores[m0 + row], s);
            }
        }
    }
}

// ================= FALLBACK: fp32-staged GEMM =================
#define LDSP 40
__global__ __launch_bounds__(256) void k_score(const float* __restrict__ enc,
        const unsigned short* __restrict__ Wb, const float* __restrict__ dp,
        const float* __restrict__ vw, float* __restrict__ scores) {
    __shared__ __align__(16) unsigned short As[128][LDSP];
    __shared__ __align__(16) unsigned short Bs[128][LDSP];
    int bid = blockIdx.x;
    int nt = bid & 7;
    int mt = bid >> 3;
    long m0 = (long)mt * 128;
    int o0 = nt * 128;
    int tid = threadIdx.x;
    int lane = tid & 63, wid = tid >> 6;
    int wm = wid >> 1, wn = wid & 1;
    int r = lane & 15, g = lane >> 4;

    f32x4 acc[4][4];
    #pragma unroll
    for (int i = 0; i < 4; ++i)
        #pragma unroll
        for (int j = 0; j < 4; ++j) acc[i][j] = (f32x4){0.f, 0.f, 0.f, 0.f};

    for (int kc = 0; kc < HH; kc += 32) {
        #pragma unroll
        for (int i = 0; i < 4; ++i) {
            int idx = tid + i * 256;
            int row = idx >> 3, kq = idx & 7;
            float4 a = *(const float4*)(enc + (m0 + row) * HH + kc + kq * 4);
            ushort4 p;
            p.x = f2bf(a.x); p.y = f2bf(a.y); p.z = f2bf(a.z); p.w = f2bf(a.w);
            *(ushort4*)(&As[row][kq * 4]) = p;
        }
        #pragma unroll
        for (int i = 0; i < 2; ++i) {
            int idx = tid + i * 256;
            int row = idx >> 2, kq = idx & 3;
            *(int4*)(&Bs[row][kq * 8]) =
                *(const int4*)(Wb + (long)(o0 + row) * HH + kc + kq * 8);
        }
        __syncthreads();
        bf16x8 af[4], bfr[4];
        #pragma unroll
        for (int mi = 0; mi < 4; ++mi)
            af[mi] = *(const bf16x8*)(&As[wm * 64 + mi * 16 + r][g * 8]);
        #pragma unroll
        for (int ni = 0; ni < 4; ++ni)
            bfr[ni] = *(const bf16x8*)(&Bs[wn * 64 + ni * 16 + r][g * 8]);
        #pragma unroll
        for (int mi = 0; mi < 4; ++mi)
            #pragma unroll
            for (int ni = 0; ni < 4; ++ni)
                acc[mi][ni] = __builtin_amdgcn_mfma_f32_16x16x32_bf16(
                    af[mi], bfr[ni], acc[mi][ni], 0, 0, 0);
        __syncthreads();
    }

    int bb = (int)(m0 >> 11);
    #pragma unroll
    for (int mi = 0; mi < 4; ++mi) {
        float vp[4] = {0.f, 0.f, 0.f, 0.f};
        #pragma unroll
        for (int ni = 0; ni < 4; ++ni) {
            int o = o0 + wn * 64 + ni * 16 + r;
            float vvs = vw[o];
            float dpvs = dp[bb * HH + o];
            #pragma unroll
            for (int j = 0; j < 4; ++j)
                vp[j] += fast_tanh(acc[mi][ni][j] + dpvs) * vvs;
        }
        #pragma unroll
        for (int j = 0; j < 4; ++j) {
            float s = vp[j];
            s += __shfl_xor(s, 1); s += __shfl_xor(s, 2);
            s += __shfl_xor(s, 4); s += __shfl_xor(s, 8);
            if (r == 0) {
                int row = wm * 64 + mi * 16 + g * 4 + j;
                atomicAdd(&scores[m0 + row], s);
            }
        }
    }
}

// ---- softmax over T per batch row, in-place ----
__global__ void k_softmax(float* __restrict__ w) {
    int b = blockIdx.x;
    float* row = w + (long)b * TT;
    int tid = threadIdx.x;
    float loc[8];
    float m = -1e30f;
    #pragma unroll
    for (int i = 0; i < 8; ++i) { loc[i] = row[tid + i * 256]; m = fmaxf(m, loc[i]); }
    #pragma unroll
    for (int off = 1; off < 64; off <<= 1) m = fmaxf(m, __shfl_xor(m, off));
    __shared__ float red[4];
    if ((tid & 63) == 0) red[tid >> 6] = m;
    __syncthreads();
    m = fmaxf(fmaxf(red[0], red[1]), fmaxf(red[2], red[3]));
    float s = 0.f;
    #pragma unroll
    for (int i = 0; i < 8; ++i) { loc[i] = __expf(loc[i] - m); s += loc[i]; }
    #pragma unroll
    for (int off = 1; off < 64; off <<= 1) s += __shfl_xor(s, off);
    __shared__ float red2[4];
    if ((tid & 63) == 0) red2[tid >> 6] = s;
    __syncthreads();
    s = red2[0] + red2[1] + red2[2] + red2[3];
    float inv = 1.0f / s;
    #pragma unroll
    for (int i = 0; i < 8; ++i) row[tid + i * 256] = loc[i] * inv;
}

// ---- context from bf16 enc: 4 h per thread, ushort4 loads ----
__global__ void k_context_bf(const unsigned short* __restrict__ encb,
                             const float* __restrict__ w, float* __restrict__ ctx) {
    int bid = blockIdx.x;             // 512 = 32 b x 16 ts
    int b = bid >> 4;
    int ts = bid & 15;
    int h = threadIdx.x * 4;
    const float* wr = w + (long)b * TT + ts * 128;
    long base = ((long)b * TT + (long)ts * 128) * HH + h;
    float a0 = 0.f, a1 = 0.f, a2 = 0.f, a3 = 0.f;
    #pragma unroll 4
    for (int t = 0; t < 128; ++t) {
        ushort4 e = *(const ushort4*)(encb + base + (long)t * HH);
        float ww = wr[t];
        a0 += ww * bf2f(e.x);
        a1 += ww * bf2f(e.y);
        a2 += ww * bf2f(e.z);
        a3 += ww * bf2f(e.w);
    }
    atomicAdd(&ctx[b * HH + h], a0);
    atomicAdd(&ctx[b * HH + h + 1], a1);
    atomicAdd(&ctx[b * HH + h + 2], a2);
    atomicAdd(&ctx[b * HH + h + 3], a3);
}

// ---- fallback context (fp32 enc) ----
__global__ void k_context(const float* __restrict__ enc, const float* __restrict__ w,
                          float* __restrict__ ctx) {
    int bid = blockIdx.x;             // 2048
    int b = bid >> 6;
    int hc = (bid >> 4) & 3;
    int ts = bid & 15;
    int h = hc * 256 + threadIdx.x;
    const float* wr = w + (long)b * TT + ts * 128;
    long base = ((long)b * TT + (long)ts * 128) * HH + h;
    float acc = 0.f;
    for (int t = 0; t < 128; ++t)
        acc += wr[t] * enc[base + (long)t * HH];
    atomicAdd(&ctx[b * HH + h], acc);
}

extern "C" void kernel_launch(void* const* d_in, const int* in_sizes, int n_in,
                              void* d_out, int out_size, void* d_ws, size_t ws_size,
                              hipStream_t stream) {
    const float* dec  = (const float*)d_in[0];
    const float* enc  = (const float*)d_in[1];
    const float* Wa_w = (const float*)d_in[2];
    const float* Wa_b = (const float*)d_in[3];
    const float* Ua_w = (const float*)d_in[4];
    const float* Ua_b = (const float*)d_in[5];
    const float* v_w  = (const float*)d_in[6];

    float* out  = (float*)d_out;
    float* ctx  = out;                 // [B][H]
    float* attn = out + BB * HH;       // [B][T]

    float* dpw = (float*)d_ws;                                        // 128 KB
    unsigned short* Wb = (unsigned short*)((char*)d_ws + 131072);     // 2 MB
    unsigned short* encb = (unsigned short*)((char*)d_ws + 131072 + 2097152); // 128 MB
    const size_t NEED = 131072ull + 2097152ull + (size_t)BB * TT * HH * 2;

    hipMemsetAsync(d_out, 0, (size_t)out_size * sizeof(float), stream);
    k_convW<<<1024, 256, 0, stream>>>(Wa_w, Wb);
    k_decproj<<<128, 256, 0, stream>>>(dec, Ua_w, Ua_b, Wa_b, dpw);

    if (ws_size >= NEED) {
        k_convEnc<<<32768, 256, 0, stream>>>(enc, encb);
        k_score_bf<<<1024, 256, 0, stream>>>(encb, Wb, dpw, v_w, attn);
        k_softmax<<<BB, 256, 0, stream>>>(attn);
        k_context_bf<<<512, 256, 0, stream>>>(encb, attn, ctx);
    } else {
        k_score<<<4096, 256, 0, stream>>>(enc, Wb, dpw, v_w, attn);
        k_softmax<<<BB, 256, 0, stream>>>(attn);
        k_context<<<2048, 256, 0, stream>>>(enc, attn, ctx);
    }
}